// Round 1
// baseline (269.354 us; speedup 1.0000x reference)
//
#include <hip/hip_runtime.h>
#include <math.h>

#define BB 128
#define TT_ 64
#define NN 81
#define MM 128
#define GG 512      // 4*M
#define TN 5184     // T*N
#define TCH 8       // timesteps per block in k2
#define NBLK2 (BB * (TT_ / TCH))   // 1024

__device__ __forceinline__ float sigmoidf_(float x) {
    return 1.0f / (1.0f + __expf(-x));
}
__device__ __forceinline__ float fast_tanh(float x) {
    float e = __expf(2.0f * x);
    return 1.0f - 2.0f / (e + 1.0f);
}

// ---------------- kernel 1: per-batch precompute hb = h0@U_lstm + b_lstm, U = X^T@Ue_w + Ue_b
__global__ __launch_bounds__(256) void k1_prep(
    const float* __restrict__ X, const float* __restrict__ h0,
    const float* __restrict__ U_lstm, const float* __restrict__ b_lstm,
    const float* __restrict__ Ue_w, const float* __restrict__ Ue_b,
    float* __restrict__ ws_hb, float* __restrict__ ws_U)
{
    __shared__ float h0l[MM];
    __shared__ float Xl[TN];
    int b = blockIdx.x;
    int tid = threadIdx.x;
    if (tid < MM) h0l[tid] = h0[b * MM + tid];
    for (int p = tid; p < TN; p += 256) Xl[p] = X[b * TN + p];
    __syncthreads();

    // hb: 512 outputs, 2 per thread
    {
        float a0 = b_lstm[tid], a1 = b_lstm[tid + 256];
        for (int j = 0; j < MM; ++j) {
            float h = h0l[j];
            a0 += h * U_lstm[j * GG + tid];
            a1 += h * U_lstm[j * GG + tid + 256];
        }
        ws_hb[b * GG + tid]       = a0;
        ws_hb[b * GG + tid + 256] = a1;
    }
    // U[b][i][k] = sum_t X[b][t][i] * Ue_w[t][k] + Ue_b[k]
    for (int p = tid; p < TN; p += 256) {
        int i = p >> 6, k = p & 63;
        float acc = Ue_b[k];
        for (int t = 0; t < TT_; ++t)
            acc += Xl[t * NN + i] * Ue_w[t * TT_ + k];
        ws_U[b * TN + p] = acc;
    }
}

// ---------------- kernel 2: gates -> h,c -> A -> scores -> softmax -> out write
__global__ __launch_bounds__(256) void k2_main(
    const float* __restrict__ X, const float* __restrict__ s0,
    const float* __restrict__ W_lstm,
    const float* __restrict__ We_w, const float* __restrict__ We_b,
    const float* __restrict__ ve_w, const float* __restrict__ ve_b,
    const float* __restrict__ ws_hb, const float* __restrict__ ws_U,
    float* __restrict__ out)
{
    __shared__ alignas(16) float sXct[NN * TCH];   // [n'][tt], transposed X chunk
    __shared__ float sHb[GG];
    __shared__ float sGU[5280];                    // union: gates[8][512]=4096 then U[81][65]=5265
    __shared__ float sHc[TCH * 256];               // [tt][ h(128) | c(128) ]
    __shared__ float sA[TCH * 65];                 // padded
    __shared__ float sSc[TCH * NN];                // scores -> alpha
    __shared__ float sVe[TT_];

    int blk = blockIdx.x;
    int b  = blk >> 3;
    int tc = blk & 7;
    int t0 = tc * TCH;
    int tid = threadIdx.x;
    float veb = ve_b[0];

    // phase 0: loads
    for (int p = tid; p < NN * TCH; p += 256) {
        float v = X[b * TN + t0 * NN + p];
        int tt = p / NN, np = p - tt * NN;
        sXct[np * TCH + tt] = v;
    }
    sHb[tid]       = ws_hb[b * GG + tid];
    sHb[tid + 256] = ws_hb[b * GG + tid + 256];
    if (tid < TT_) sVe[tid] = ve_w[tid];
    __syncthreads();

    // phase 1: gates[tt][g] = sum_n X[b,t0+tt,n] * W_lstm[n][g] + hb[g]
    float acc0[TCH], acc1[TCH];
    {
        float h0v = sHb[tid], h1v = sHb[tid + 256];
#pragma unroll
        for (int tt = 0; tt < TCH; ++tt) { acc0[tt] = h0v; acc1[tt] = h1v; }
        for (int n = 0; n < NN; ++n) {
            float w0 = W_lstm[n * GG + tid];
            float w1 = W_lstm[n * GG + tid + 256];
            const float4* xr4 = (const float4*)&sXct[n * TCH];
            float4 xa = xr4[0];
            float4 xb = xr4[1];
            acc0[0] += xa.x * w0; acc1[0] += xa.x * w1;
            acc0[1] += xa.y * w0; acc1[1] += xa.y * w1;
            acc0[2] += xa.z * w0; acc1[2] += xa.z * w1;
            acc0[3] += xa.w * w0; acc1[3] += xa.w * w1;
            acc0[4] += xb.x * w0; acc1[4] += xb.x * w1;
            acc0[5] += xb.y * w0; acc1[5] += xb.y * w1;
            acc0[6] += xb.z * w0; acc1[6] += xb.z * w1;
            acc0[7] += xb.w * w0; acc1[7] += xb.w * w1;
        }
    }
#pragma unroll
    for (int tt = 0; tt < TCH; ++tt) {
        sGU[tt * GG + tid]       = acc0[tt];
        sGU[tt * GG + tid + 256] = acc1[tt];
    }
    __syncthreads();

    // phase 1.5: activations -> h, c
    for (int p = tid; p < TCH * MM; p += 256) {
        int tt = p >> 7, u = p & 127;
        const float* gr = &sGU[tt * GG];
        float gi = sigmoidf_(gr[u]);
        float gf = sigmoidf_(gr[MM + u]);
        float gg = fast_tanh(gr[2 * MM + u]);
        float go = sigmoidf_(gr[3 * MM + u]);
        float c  = gf * s0[b * MM + u] + gi * gg;
        float h  = go * fast_tanh(c);
        sHc[tt * 256 + u]       = h;
        sHc[tt * 256 + 128 + u] = c;
    }
    __syncthreads();   // gates region now dead; sHc live

    // phase 2: A[tt][k] = sum_j hc[tt][j] * We_w[j][k] + We_b[k]
    {
        int k  = tid & 63;
        int th = tid >> 6;   // 0..3 -> handles tt=th and tt=th+4
        float a0 = We_b[k], a1 = a0;
        for (int j = 0; j < 256; ++j) {
            float w = We_w[j * TT_ + k];
            a0 += sHc[th * 256 + j]       * w;
            a1 += sHc[(th + 4) * 256 + j] * w;
        }
        sA[th * 65 + k]       = a0;
        sA[(th + 4) * 65 + k] = a1;
    }
    // phase 2.5: load U[b] into sGU (padded to 65), overwriting gates
    for (int p = tid; p < TN; p += 256) {
        int i = p >> 6, k = p & 63;
        sGU[i * 65 + k] = ws_U[b * TN + p];
    }
    __syncthreads();

    // phase 3: scores[tt][i] = sum_k tanh(A[tt][k] + U[i][k]) * ve[k] + ve_b
    {
        int wv = tid >> 6;
        int l  = tid & 63;
#pragma unroll
        for (int hh = 0; hh < 2; ++hh) {
            int tt = wv + hh * 4;
            const float* Ar = &sA[tt * 65];
#pragma unroll
            for (int pass = 0; pass < 2; ++pass) {
                int i = l + pass * 64;
                if (i < NN) {
                    const float* Ur = &sGU[i * 65];
                    float acc = 0.f;
                    for (int k = 0; k < TT_; ++k)
                        acc += fast_tanh(Ar[k] + Ur[k]) * sVe[k];
                    sSc[tt * NN + i] = acc + veb;
                }
            }
        }
    }
    __syncthreads();

    // phase 3.5: softmax over i (81), one wave owns rows tt=wv and wv+4
    {
        int wv = tid >> 6;
        int l  = tid & 63;
#pragma unroll
        for (int hh = 0; hh < 2; ++hh) {
            int tt = wv + hh * 4;
            float a  = sSc[tt * NN + l];
            bool v2  = (l + 64 < NN);
            float b2 = v2 ? sSc[tt * NN + l + 64] : -1e30f;
            float mx = fmaxf(a, b2);
            for (int d = 32; d >= 1; d >>= 1) mx = fmaxf(mx, __shfl_xor(mx, d, 64));
            float ea = __expf(a - mx);
            float eb = v2 ? __expf(b2 - mx) : 0.f;
            float s = ea + eb;
            for (int d = 32; d >= 1; d >>= 1) s += __shfl_xor(s, d, 64);
            float inv = 1.f / s;
            sSc[tt * NN + l] = ea * inv;
            if (v2) sSc[tt * NN + l + 64] = eb * inv;
        }
    }
    __syncthreads();

    // phase 4: out[t0+tt, b, t2, i] = X[b, t2, i] * alpha[tt][i]
    {
        const float* Xb = &X[b * TN];
        for (int j = tid; j < TN; j += 256) {
            float x = Xb[j];
            int i = j % NN;   // compiler magic-divide
#pragma unroll
            for (int tt = 0; tt < TCH; ++tt) {
                out[((size_t)(t0 + tt) * BB + b) * TN + j] = x * sSc[tt * NN + i];
            }
        }
    }
}

extern "C" void kernel_launch(void* const* d_in, const int* in_sizes, int n_in,
                              void* d_out, int out_size, void* d_ws, size_t ws_size,
                              hipStream_t stream) {
    const float* X      = (const float*)d_in[0];
    const float* h0     = (const float*)d_in[1];
    const float* s0     = (const float*)d_in[2];
    const float* W_lstm = (const float*)d_in[3];
    const float* U_lstm = (const float*)d_in[4];
    const float* b_lstm = (const float*)d_in[5];
    const float* We_w   = (const float*)d_in[6];
    const float* We_b   = (const float*)d_in[7];
    const float* Ue_w   = (const float*)d_in[8];
    const float* Ue_b   = (const float*)d_in[9];
    const float* ve_w   = (const float*)d_in[10];
    const float* ve_b   = (const float*)d_in[11];
    float* out = (float*)d_out;

    float* ws    = (float*)d_ws;
    float* ws_hb = ws;                  // B*512 floats
    float* ws_U  = ws + BB * GG;        // B*5184 floats

    k1_prep<<<BB, 256, 0, stream>>>(X, h0, U_lstm, b_lstm, Ue_w, Ue_b, ws_hb, ws_U);
    k2_main<<<NBLK2, 256, 0, stream>>>(X, s0, W_lstm, We_w, We_b, ve_w, ve_b,
                                       ws_hb, ws_U, out);
}

// Round 2
// 250.411 us; speedup vs baseline: 1.0756x; 1.0756x over previous
//
#include <hip/hip_runtime.h>
#include <math.h>

#define BB 128
#define TT_ 64
#define NN 81
#define MM 128
#define GG 512      // 4*M
#define TN 5184     // T*N
#define TCH 8       // timesteps per block in k2
#define NBLK2 (BB * (TT_ / TCH))   // 1024
#define SC_ 2.8853900817779268f    // 2*log2(e): exp2(SC*z) = e^{2z}

__device__ __forceinline__ float sigmoidf_(float x) {
    return 1.0f / (1.0f + __expf(-x));
}
__device__ __forceinline__ float fast_tanh(float x) {
    float e = __expf(2.0f * x);
    return 1.0f - 2.0f / (e + 1.0f);
}

// ---------------- kernel 1: 512 blocks (4 per batch).
// Each block: U[b][i][k] for k in [q*16, q*16+16), all i.  q==0 also does hb.
__global__ __launch_bounds__(256) void k1_prep(
    const float* __restrict__ X, const float* __restrict__ h0,
    const float* __restrict__ U_lstm, const float* __restrict__ b_lstm,
    const float* __restrict__ Ue_w, const float* __restrict__ Ue_b,
    float* __restrict__ ws_hb, float* __restrict__ ws_U)
{
    __shared__ float Xl[TN];          // 20736 B
    __shared__ float sUe[64 * 16];    // 4096 B, Ue_w column block
    __shared__ float h0l[MM];

    int blk = blockIdx.x;
    int b = blk >> 2;
    int q = blk & 3;
    int tid = threadIdx.x;

    for (int p = tid; p < TN; p += 256) Xl[p] = X[b * TN + p];
    for (int p = tid; p < 1024; p += 256) {
        int t = p >> 4, kl = p & 15;
        sUe[p] = Ue_w[t * TT_ + q * 16 + kl];
    }
    if (q == 0 && tid < MM) h0l[tid] = h0[b * MM + tid];
    __syncthreads();

    if (q == 0) {
        // hb = h0 @ U_lstm + b_lstm, thread owns gate cols 2tid, 2tid+1
        float2 bl = ((const float2*)b_lstm)[tid];
        float a0 = bl.x, a1 = bl.y;
        for (int j = 0; j < MM; ++j) {
            float h = h0l[j];
            float2 w = ((const float2*)&U_lstm[j * GG])[tid];
            a0 += h * w.x;
            a1 += h * w.y;
        }
        ((float2*)&ws_hb[b * GG])[tid] = make_float2(a0, a1);
    }

    // U[b][i][k] = sum_t X[b][t][i] * Ue_w[t][k] + Ue_b[k]
    int kl = tid & 15;
    int k  = q * 16 + kl;
    int ir = tid >> 4;
    float ueb = Ue_b[k];
#pragma unroll
    for (int pass = 0; pass < 6; ++pass) {
        int i = pass * 16 + ir;
        if (i < NN) {
            float acc = ueb;
#pragma unroll 8
            for (int t = 0; t < TT_; ++t)
                acc += Xl[t * NN + i] * sUe[t * 16 + kl];
            ws_U[b * TN + i * 64 + k] = acc;
        }
    }
}

// ---------------- kernel 2: gates -> h,c -> A -> scores -> softmax -> out write
__global__ __launch_bounds__(256) void k2_main(
    const float* __restrict__ X, const float* __restrict__ s0,
    const float* __restrict__ W_lstm,
    const float* __restrict__ We_w, const float* __restrict__ We_b,
    const float* __restrict__ ve_w, const float* __restrict__ ve_b,
    const float* __restrict__ ws_hb, const float* __restrict__ ws_U,
    float* __restrict__ out)
{
    __shared__ alignas(16) float sXct[NN * TCH];   // [n'][tt], transposed X chunk
    __shared__ float sGU[5280];                    // union: gates[8][512]=4096, then U'[81][65]
    __shared__ float sHc[TCH * 256];               // [tt][ h(128) | c(128) ]
    __shared__ float sA[TCH * 65];                 // A' (pre-scaled), padded
    __shared__ float sSc[TCH * NN];                // scores -> alpha
    __shared__ float sVe[TT_];

    int blk = blockIdx.x;
    int b  = blk >> 3;
    int tc = blk & 7;
    int t0 = tc * TCH;
    int tid = threadIdx.x;
    float veb = ve_b[0];

    // phase 0: loads
    for (int p = tid; p < NN * TCH; p += 256) {
        float v = X[b * TN + t0 * NN + p];
        int tt = p / NN, np = p - tt * NN;
        sXct[np * TCH + tt] = v;
    }
    if (tid < TT_) sVe[tid] = ve_w[tid];
    __syncthreads();

    // phase 1: gates[tt][g] = sum_n X[b,t0+tt,n] * W_lstm[n][g] + hb[g]
    // thread owns gate cols 2tid, 2tid+1
    float acc0[TCH], acc1[TCH];
    {
        float2 hbv = ((const float2*)&ws_hb[b * GG])[tid];
#pragma unroll
        for (int tt = 0; tt < TCH; ++tt) { acc0[tt] = hbv.x; acc1[tt] = hbv.y; }
        for (int n = 0; n < NN; ++n) {
            float2 w = ((const float2*)&W_lstm[n * GG])[tid];
            const float4* xr4 = (const float4*)&sXct[n * TCH];
            float4 xa = xr4[0];
            float4 xb = xr4[1];
            acc0[0] += xa.x * w.x; acc1[0] += xa.x * w.y;
            acc0[1] += xa.y * w.x; acc1[1] += xa.y * w.y;
            acc0[2] += xa.z * w.x; acc1[2] += xa.z * w.y;
            acc0[3] += xa.w * w.x; acc1[3] += xa.w * w.y;
            acc0[4] += xb.x * w.x; acc1[4] += xb.x * w.y;
            acc0[5] += xb.y * w.x; acc1[5] += xb.y * w.y;
            acc0[6] += xb.z * w.x; acc1[6] += xb.z * w.y;
            acc0[7] += xb.w * w.x; acc1[7] += xb.w * w.y;
        }
    }
#pragma unroll
    for (int tt = 0; tt < TCH; ++tt) {
        ((float2*)&sGU[tt * GG])[tid] = make_float2(acc0[tt], acc1[tt]);
    }
    __syncthreads();

    // phase 1.5: activations -> h, c
    for (int p = tid; p < TCH * MM; p += 256) {
        int tt = p >> 7, u = p & 127;
        const float* gr = &sGU[tt * GG];
        float gi = sigmoidf_(gr[u]);
        float gf = sigmoidf_(gr[MM + u]);
        float gg = fast_tanh(gr[2 * MM + u]);
        float go = sigmoidf_(gr[3 * MM + u]);
        float c  = gf * s0[b * MM + u] + gi * gg;
        float h  = go * fast_tanh(c);
        sHc[tt * 256 + u]       = h;
        sHc[tt * 256 + 128 + u] = c;
    }
    __syncthreads();   // gates region now dead; sHc live

    // phase 2: A'[tt][k] = SC * (sum_j hc[tt][j] * We_w[j][k] + We_b[k])
    {
        int k  = tid & 63;
        int th = tid >> 6;   // handles tt=th and tt=th+4
        float a0 = We_b[k], a1 = a0;
        for (int j = 0; j < 256; ++j) {
            float w = We_w[j * TT_ + k];
            a0 += sHc[th * 256 + j]       * w;
            a1 += sHc[(th + 4) * 256 + j] * w;
        }
        sA[th * 65 + k]       = a0 * SC_;
        sA[(th + 4) * 65 + k] = a1 * SC_;
    }
    // phase 2.5: load U'[b] = SC*U into sGU (padded to 65), overwriting gates
    for (int p = tid; p < TN; p += 256) {
        int i = p >> 6, k = p & 63;
        sGU[i * 65 + k] = ws_U[b * TN + p] * SC_;
    }
    __syncthreads();

    // phase 3: score[tt][i] = sumVe - 2*sum_k ve[k]/(exp2(A'+U')+1) + ve_b
    {
        int wv = tid >> 6;
        int l  = tid & 63;
        float sumVe = 0.f;
        for (int k = 0; k < TT_; ++k) sumVe += sVe[k];
#pragma unroll
        for (int hh = 0; hh < 2; ++hh) {
            int tt = wv + hh * 4;
            const float* Ar = &sA[tt * 65];
#pragma unroll
            for (int pass = 0; pass < 2; ++pass) {
                int i = l + pass * 64;
                if (i < NN) {
                    const float* Ur = &sGU[i * 65];
                    float acc = 0.f;
#pragma unroll 8
                    for (int k = 0; k < TT_; ++k) {
                        float s = Ar[k] + Ur[k];
                        float e = exp2f(s);
                        float r = __builtin_amdgcn_rcpf(e + 1.0f);
                        acc = fmaf(sVe[k], r, acc);
                    }
                    sSc[tt * NN + i] = sumVe - 2.0f * acc + veb;
                }
            }
        }
    }
    __syncthreads();

    // phase 3.5: softmax over i (81), one wave owns rows tt=wv and wv+4
    {
        int wv = tid >> 6;
        int l  = tid & 63;
#pragma unroll
        for (int hh = 0; hh < 2; ++hh) {
            int tt = wv + hh * 4;
            float a  = sSc[tt * NN + l];
            bool v2  = (l + 64 < NN);
            float b2 = v2 ? sSc[tt * NN + l + 64] : -1e30f;
            float mx = fmaxf(a, b2);
            for (int d = 32; d >= 1; d >>= 1) mx = fmaxf(mx, __shfl_xor(mx, d, 64));
            float ea = __expf(a - mx);
            float eb = v2 ? __expf(b2 - mx) : 0.f;
            float s = ea + eb;
            for (int d = 32; d >= 1; d >>= 1) s += __shfl_xor(s, d, 64);
            float inv = 1.f / s;
            sSc[tt * NN + l] = ea * inv;
            if (v2) sSc[tt * NN + l + 64] = eb * inv;
        }
    }
    __syncthreads();

    // phase 4: out[t0+tt, b, t2, i] = X[b, t2, i] * alpha[tt][i]
    {
        const float* Xb = &X[b * TN];
        for (int j = tid; j < TN; j += 256) {
            float x = Xb[j];
            int i = j % NN;   // compiler magic-divide
#pragma unroll
            for (int tt = 0; tt < TCH; ++tt) {
                out[((size_t)(t0 + tt) * BB + b) * TN + j] = x * sSc[tt * NN + i];
            }
        }
    }
}

extern "C" void kernel_launch(void* const* d_in, const int* in_sizes, int n_in,
                              void* d_out, int out_size, void* d_ws, size_t ws_size,
                              hipStream_t stream) {
    const float* X      = (const float*)d_in[0];
    const float* h0     = (const float*)d_in[1];
    const float* s0     = (const float*)d_in[2];
    const float* W_lstm = (const float*)d_in[3];
    const float* U_lstm = (const float*)d_in[4];
    const float* b_lstm = (const float*)d_in[5];
    const float* We_w   = (const float*)d_in[6];
    const float* We_b   = (const float*)d_in[7];
    const float* Ue_w   = (const float*)d_in[8];
    const float* Ue_b   = (const float*)d_in[9];
    const float* ve_w   = (const float*)d_in[10];
    const float* ve_b   = (const float*)d_in[11];
    float* out = (float*)d_out;

    float* ws    = (float*)d_ws;
    float* ws_hb = ws;                  // B*512 floats
    float* ws_U  = ws + BB * GG;        // B*5184 floats

    k1_prep<<<BB * 4, 256, 0, stream>>>(X, h0, U_lstm, b_lstm, Ue_w, Ue_b, ws_hb, ws_U);
    k2_main<<<NBLK2, 256, 0, stream>>>(X, s0, W_lstm, We_w, We_b, ve_w, ve_b,
                                       ws_hb, ws_U, out);
}

// Round 3
// 249.962 us; speedup vs baseline: 1.0776x; 1.0018x over previous
//
#include <hip/hip_runtime.h>
#include <math.h>

#define BB 128
#define TT_ 64
#define NN 81
#define MM 128
#define GG 512      // 4*M
#define TN 5184     // T*N
#define TCH 8       // timesteps per block in k2
#define NBLK2 (BB * (TT_ / TCH))   // 1024
#define SC_ 2.8853900817779268f    // 2*log2(e): exp2(SC*z) = e^{2z}

__device__ __forceinline__ float sigmoidf_(float x) {
    return 1.0f / (1.0f + __expf(-x));
}
__device__ __forceinline__ float fast_tanh(float x) {
    float e = __expf(2.0f * x);
    return 1.0f - 2.0f / (e + 1.0f);
}

// ---------------- kernel 1: 512 blocks (4 per batch).
// Each block: U'[b][i][k] = SC*(sum_t X[t][i]*Ue_w[t][k] + Ue_b[k]) for k in q*16..+16.
// q==0 also does hb = h0@U_lstm + b_lstm.
__global__ __launch_bounds__(256) void k1_prep(
    const float* __restrict__ X, const float* __restrict__ h0,
    const float* __restrict__ U_lstm, const float* __restrict__ b_lstm,
    const float* __restrict__ Ue_w, const float* __restrict__ Ue_b,
    float* __restrict__ ws_hb, float* __restrict__ ws_U)
{
    __shared__ float Xl[TN];
    __shared__ float sUe[64 * 16];
    __shared__ float h0l[MM];

    int blk = blockIdx.x;
    int b = blk >> 2;
    int q = blk & 3;
    int tid = threadIdx.x;

    for (int p = tid; p < TN; p += 256) Xl[p] = X[b * TN + p];
    for (int p = tid; p < 1024; p += 256) {
        int t = p >> 4, kl = p & 15;
        sUe[p] = Ue_w[t * TT_ + q * 16 + kl];
    }
    if (q == 0 && tid < MM) h0l[tid] = h0[b * MM + tid];
    __syncthreads();

    if (q == 0) {
        float2 bl = ((const float2*)b_lstm)[tid];
        float a0 = bl.x, a1 = bl.y;
        for (int j = 0; j < MM; ++j) {
            float h = h0l[j];
            float2 w = ((const float2*)&U_lstm[j * GG])[tid];
            a0 += h * w.x;
            a1 += h * w.y;
        }
        ((float2*)&ws_hb[b * GG])[tid] = make_float2(a0, a1);
    }

    int kl = tid & 15;
    int k  = q * 16 + kl;
    int ir = tid >> 4;
    float ueb = Ue_b[k];
#pragma unroll
    for (int pass = 0; pass < 6; ++pass) {
        int i = pass * 16 + ir;
        if (i < NN) {
            float acc = ueb;
#pragma unroll 8
            for (int t = 0; t < TT_; ++t)
                acc += Xl[t * NN + i] * sUe[t * 16 + kl];
            ws_U[b * TN + i * 64 + k] = acc * SC_;   // pre-scaled
        }
    }
}

// ---------------- kernel 2: 3-barrier register pipeline
__global__ __launch_bounds__(256, 4) void k2_main(
    const float* __restrict__ X, const float* __restrict__ s0,
    const float* __restrict__ W_lstm,
    const float* __restrict__ We_w, const float* __restrict__ We_b,
    const float* __restrict__ ve_w, const float* __restrict__ ve_b,
    const float* __restrict__ ws_hb, const float* __restrict__ ws_U,
    float* __restrict__ out)
{
    __shared__ alignas(16) float sXct[NN * TCH];   // [n][tt] transposed X chunk (648)
    __shared__ float sU[NN * 65];                  // U' pre-scaled, padded (5265)
    __shared__ float sHc[TCH * 256];               // [tt][ h | c ] (2048)
    __shared__ float sA[TCH * 65];                 // A' pre-scaled, padded (520)
    __shared__ float sSc[TCH * NN];                // alpha (648)
    __shared__ float sVe[TT_];

    int blk = blockIdx.x;
    int b  = blk >> 3;
    int tc = blk & 7;
    int t0 = tc * TCH;
    int tid = threadIdx.x;
    int u    = tid & 127;
    int half = tid >> 7;        // tt block: half*4 .. half*4+3
    float veb = ve_b[0];

    // ---- stage: issue all independent global loads up front
    float hb0 = ws_hb[b * GG + u];
    float hb1 = ws_hb[b * GG + 128 + u];
    float hb2 = ws_hb[b * GG + 256 + u];
    float hb3 = ws_hb[b * GG + 384 + u];
    float s0v = s0[b * MM + u];

    for (int p = tid; p < NN * TCH; p += 256) {
        float v = X[b * TN + t0 * NN + p];
        int tt = p / NN, np = p - tt * NN;
        sXct[np * TCH + tt] = v;
    }
    for (int p = tid; p < TN; p += 256) {
        int i = p >> 6, k = p & 63;
        sU[i * 65 + k] = ws_U[b * TN + p];
    }
    if (tid < TT_) sVe[tid] = ve_w[tid];
    __syncthreads();                                  // B1

    // ---- phase 1: gates in registers. thread owns unit u, tts half*4..+3, all 4 gates.
    float acc[4][4];
#pragma unroll
    for (int r = 0; r < 4; ++r) {
        acc[r][0] = hb0; acc[r][1] = hb1; acc[r][2] = hb2; acc[r][3] = hb3;
    }
    {
        const float* Wl = &W_lstm[u];
        for (int n = 0; n < NN; ++n) {
            float w0 = Wl[n * GG];
            float w1 = Wl[n * GG + 128];
            float w2 = Wl[n * GG + 256];
            float w3 = Wl[n * GG + 384];
            float4 xv = *(const float4*)&sXct[n * TCH + 4 * half];
            acc[0][0] += xv.x * w0; acc[0][1] += xv.x * w1; acc[0][2] += xv.x * w2; acc[0][3] += xv.x * w3;
            acc[1][0] += xv.y * w0; acc[1][1] += xv.y * w1; acc[1][2] += xv.y * w2; acc[1][3] += xv.y * w3;
            acc[2][0] += xv.z * w0; acc[2][1] += xv.z * w1; acc[2][2] += xv.z * w2; acc[2][3] += xv.z * w3;
            acc[3][0] += xv.w * w0; acc[3][1] += xv.w * w1; acc[3][2] += xv.w * w2; acc[3][3] += xv.w * w3;
        }
    }
    // ---- activations in registers -> sHc
#pragma unroll
    for (int r = 0; r < 4; ++r) {
        int tt = 4 * half + r;
        float gi = sigmoidf_(acc[r][0]);
        float gf = sigmoidf_(acc[r][1]);
        float gg = fast_tanh(acc[r][2]);
        float go = sigmoidf_(acc[r][3]);
        float c  = gf * s0v + gi * gg;
        float h  = go * fast_tanh(c);
        sHc[tt * 256 + u]       = h;
        sHc[tt * 256 + 128 + u] = c;
    }
    __syncthreads();                                  // B2

    // ---- wave-local from here to alpha. wave wv owns tt = wv and wv+4.
    int wv = tid >> 6;
    int l  = tid & 63;

    // phase 2: A'[tt][k] = SC*(sum_j hc[tt][j]*We_w[j][k] + We_b[k]), k = l
    {
        float a0 = We_b[l], a1 = a0;
        const float* Wep = &We_w[l];
        for (int j = 0; j < 256; ++j) {
            float w  = Wep[j * TT_];
            a0 += sHc[wv * 256 + j]       * w;
            a1 += sHc[(wv + 4) * 256 + j] * w;
        }
        sA[wv * 65 + l]       = a0 * SC_;
        sA[(wv + 4) * 65 + l] = a1 * SC_;
    }
    // sumVe via wave reduce
    float sumVe;
    {
        float sv = sVe[l];
        sumVe = sv;
        for (int d = 32; d >= 1; d >>= 1) sumVe += __shfl_xor(sumVe, d, 64);
    }

    // phase 3 + softmax fused, per owned tt
#pragma unroll
    for (int hh = 0; hh < 2; ++hh) {
        int tt = wv + hh * 4;
        const float* Ar = &sA[tt * 65];
        float sc0, sc1;
        {
            const float* Ur = &sU[l * 65];
            float a2 = 0.f;
#pragma unroll 8
            for (int k = 0; k < TT_; ++k) {
                float s = Ar[k] + Ur[k];
                float e = exp2f(s);
                float r2 = __builtin_amdgcn_rcpf(e + 1.0f);
                a2 = fmaf(sVe[k], r2, a2);
            }
            sc0 = sumVe - 2.0f * a2 + veb;
        }
        bool v2 = (l + 64 < NN);
        if (v2) {
            const float* Ur = &sU[(l + 64) * 65];
            float a2 = 0.f;
#pragma unroll 8
            for (int k = 0; k < TT_; ++k) {
                float s = Ar[k] + Ur[k];
                float e = exp2f(s);
                float r2 = __builtin_amdgcn_rcpf(e + 1.0f);
                a2 = fmaf(sVe[k], r2, a2);
            }
            sc1 = sumVe - 2.0f * a2 + veb;
        } else {
            sc1 = -1e30f;
        }
        // softmax over the 81 scores of row tt
        float mx = fmaxf(sc0, sc1);
        for (int d = 32; d >= 1; d >>= 1) mx = fmaxf(mx, __shfl_xor(mx, d, 64));
        float ea = __expf(sc0 - mx);
        float eb = v2 ? __expf(sc1 - mx) : 0.f;
        float s = ea + eb;
        for (int d = 32; d >= 1; d >>= 1) s += __shfl_xor(s, d, 64);
        float inv = 1.f / s;
        sSc[tt * NN + l] = ea * inv;
        if (v2) sSc[tt * NN + l + 64] = eb * inv;
    }
    __syncthreads();                                  // B3

    // ---- phase 4: out[t0+tt, b, t2, i] = X[b, t2, i] * alpha[tt][i]
    {
        const float* Xb = &X[b * TN];
        for (int j = tid; j < TN; j += 256) {
            float x = Xb[j];
            int i = j % NN;
#pragma unroll
            for (int tt = 0; tt < TCH; ++tt) {
                out[((size_t)(t0 + tt) * BB + b) * TN + j] = x * sSc[tt * NN + i];
            }
        }
    }
}

extern "C" void kernel_launch(void* const* d_in, const int* in_sizes, int n_in,
                              void* d_out, int out_size, void* d_ws, size_t ws_size,
                              hipStream_t stream) {
    const float* X      = (const float*)d_in[0];
    const float* h0     = (const float*)d_in[1];
    const float* s0     = (const float*)d_in[2];
    const float* W_lstm = (const float*)d_in[3];
    const float* U_lstm = (const float*)d_in[4];
    const float* b_lstm = (const float*)d_in[5];
    const float* We_w   = (const float*)d_in[6];
    const float* We_b   = (const float*)d_in[7];
    const float* Ue_w   = (const float*)d_in[8];
    const float* Ue_b   = (const float*)d_in[9];
    const float* ve_w   = (const float*)d_in[10];
    const float* ve_b   = (const float*)d_in[11];
    float* out = (float*)d_out;

    float* ws    = (float*)d_ws;
    float* ws_hb = ws;                  // B*512 floats
    float* ws_U  = ws + BB * GG;        // B*5184 floats

    k1_prep<<<BB * 4, 256, 0, stream>>>(X, h0, U_lstm, b_lstm, Ue_w, Ue_b, ws_hb, ws_U);
    k2_main<<<NBLK2, 256, 0, stream>>>(X, s0, W_lstm, We_w, We_b, ve_w, ve_b,
                                       ws_hb, ws_U, out);
}